// Round 2
// baseline (1028.304 us; speedup 1.0000x reference)
//
#include <hip/hip_runtime.h>

#define NN 50000
#define NE 800000
#define KD 256
#define CD 128
#define NB 196            // scan chunks: 196*256 = 50176 >= NN
#define GEMM_BLOCKS 782   // (NN+63)/64 GEMM tiles
#define HIST_BLOCKS 3125  // (NE+255)/256 edge chunks
#define GRID 1536         // 6 blocks/CU x 256 CUs, guaranteed co-resident
#define NGROUP 12500      // NN/4 aggregate groups (4 nodes/block-pass)

typedef __attribute__((ext_vector_type(8))) short short8;
typedef __attribute__((ext_vector_type(4))) float floatx4;

__device__ inline unsigned short f2bf(float f) {
    unsigned u = __float_as_uint(f);
    unsigned r = (u + 0x7FFFu + ((u >> 16) & 1u)) >> 16;   // RNE
    return (unsigned short)r;
}
__device__ inline float bf2f_lo(unsigned u) { return __uint_as_float(u << 16); }
__device__ inline float bf2f_hi(unsigned u) { return __uint_as_float(u & 0xFFFF0000u); }

// Device-scope grid barrier. __threadfence() at agent scope emits the L2
// writeback (release) / invalidate (acquire) required across non-coherent
// XCDs on gfx950. Requires all GRID blocks co-resident (launch_bounds).
__device__ inline void gridbar(unsigned* ctr) {
    __syncthreads();
    if (threadIdx.x == 0) {
        __threadfence();                      // release: writeback dirty L2
        atomicAdd(ctr, 1u);                   // device-scope RMW
        while (__hip_atomic_load(ctr, __ATOMIC_RELAXED, __HIP_MEMORY_SCOPE_AGENT) < GRID)
            __builtin_amdgcn_s_sleep(1);
        __threadfence();                      // acquire: invalidate stale L2
    }
    __syncthreads();
}

__global__ __launch_bounds__(256, 6) void mega(
        const float* __restrict__ x, const int* __restrict__ row,
        const int* __restrict__ col, const float* __restrict__ ew,
        const float* __restrict__ W, const float* __restrict__ bias,
        const float* __restrict__ alpha, float* __restrict__ out,
        unsigned* __restrict__ packedAll, int* __restrict__ start,
        int* __restrict__ locals, int* __restrict__ partials,
        float* __restrict__ dinv, unsigned short* __restrict__ rank,
        int4* __restrict__ base4, unsigned* __restrict__ meta,
        unsigned short* __restrict__ Wt, unsigned short* __restrict__ hb,
        unsigned* __restrict__ bars) {
    __shared__ unsigned short As[64][40];
    __shared__ unsigned short Bs[128][40];
    const int tid = threadIdx.x;
    const int bx  = blockIdx.x;

    // ========== p0: zero histogram shadows (blocks 0..781) + W transpose
    // (last 32 blocks, aliasing As as a 32x33 tile)
    {
        const int z = bx * 256 + tid;
        if (z < 4 * NN) packedAll[z] = 0u;
    }
    if (bx >= GRID - 32) {
        unsigned short (*t)[33] = (unsigned short (*)[33])(&As[0][0]);
        const int b2 = bx - (GRID - 32);       // [0,32): 8 k-tiles x 4 n-tiles
        const int bk = (b2 & 7) * 32;
        const int bn = (b2 >> 3) * 32;
        const int tx = tid & 31;
        const int ty = tid >> 5;
#pragma unroll
        for (int i = 0; i < 32; i += 8)
            t[ty + i][tx] = f2bf(W[(size_t)(bk + ty + i) * CD + bn + tx]);
        __syncthreads();
#pragma unroll
        for (int i = 0; i < 32; i += 8)
            Wt[(size_t)(bn + ty + i) * KD + bk + tx] = t[tx][ty + i];
    }
    gridbar(bars + 0);

    // ========== p1: GEMM tiles (units 0..781) + hist chunks (rest), mixed
    // grid-stride so GEMM starts immediately on blocks 0..781 and hist's
    // atomic latency hides under the MFMA work (round-0's proven overlap).
    for (int u = bx; u < GEMM_BLOCKS + HIST_BLOCKS; u += GRID) {
        if (u < GEMM_BLOCKS) {
            const int wave = tid >> 6;
            const int lane = tid & 63;
            const int row0 = u * 64;
            const int m0   = wave * 16;
            const int lr   = lane & 15;
            const int quad = lane >> 4;
            const int ar = tid >> 2;
            const int aq = tid & 3;
            const int bn = tid >> 1;
            const int bh = (tid & 1) * 16;

            const int gr = row0 + ar;
            const bool ok = gr < NN;
            const float* xb = x + (size_t)gr * KD + aq * 8;
            const unsigned short* wb = Wt + (size_t)bn * KD + bh;

            floatx4 acc[8];
#pragma unroll
            for (int nt = 0; nt < 8; nt++) acc[nt] = (floatx4){0.f, 0.f, 0.f, 0.f};

            float4 f0 = {0.f,0.f,0.f,0.f}, f1 = {0.f,0.f,0.f,0.f};
            short8 wv0, wv1;
            if (ok) { f0 = *(const float4*)xb; f1 = *(const float4*)(xb + 4); }
            wv0 = *(const short8*)wb;
            wv1 = *(const short8*)(wb + 8);

#pragma unroll
            for (int kt = 0; kt < 8; kt++) {
                union { short8 v; unsigned short us[8]; } av;
                if (ok) {
                    av.us[0] = f2bf(f0.x); av.us[1] = f2bf(f0.y);
                    av.us[2] = f2bf(f0.z); av.us[3] = f2bf(f0.w);
                    av.us[4] = f2bf(f1.x); av.us[5] = f2bf(f1.y);
                    av.us[6] = f2bf(f1.z); av.us[7] = f2bf(f1.w);
                } else {
                    av.v = (short8){0,0,0,0,0,0,0,0};
                }
                *(short8*)&As[ar][aq * 8] = av.v;
                *(short8*)&Bs[bn][bh]     = wv0;
                *(short8*)&Bs[bn][bh + 8] = wv1;
                __syncthreads();
                if (kt < 7) {
                    const float* xp = xb + (kt + 1) * 32;
                    if (ok) { f0 = *(const float4*)xp; f1 = *(const float4*)(xp + 4); }
                    const unsigned short* wp = wb + (kt + 1) * 32;
                    wv0 = *(const short8*)wp;
                    wv1 = *(const short8*)(wp + 8);
                }
                short8 af = *(const short8*)&As[m0 + lr][quad * 8];
#pragma unroll
                for (int nt = 0; nt < 8; nt++) {
                    short8 bfr = *(const short8*)&Bs[nt * 16 + lr][quad * 8];
                    acc[nt] = __builtin_amdgcn_mfma_f32_16x16x32_bf16(af, bfr, acc[nt], 0, 0, 0);
                }
                __syncthreads();
            }
#pragma unroll
            for (int i = 0; i < 4; i++) {
                const int grow = row0 + m0 + quad * 4 + i;
                if (grow < NN) {
                    unsigned short* hp = hb + (size_t)grow * CD + lr;
#pragma unroll
                    for (int nt = 0; nt < 8; nt++)
                        hp[nt * 16] = f2bf(acc[nt][i]);
                }
            }
        } else {
            // hist: u32 packed {count:8 | sum(ew) Q6.18:24}, 4 shadow copies,
            // copy = chunk&3 == (e>>8)&3 (matches p4's formula)
            const int h = u - GEMM_BLOCKS;
            const int e = h * 256 + tid;
            if (e < NE) {
                unsigned* packed = packedAll + (size_t)(h & 3) * NN;
                unsigned p = (1u << 24) + (unsigned)(ew[e] * 262144.0f);
                unsigned old = atomicAdd(&packed[col[e]], p);
                rank[e] = (unsigned short)(old >> 24);
            }
        }
    }
    gridbar(bars + 1);

    // ========== p2: per-chunk exclusive scan of counts (196 chunks)
    for (int b = bx; b < NB; b += GRID) {
        int* sm = (int*)(&As[0][0]);
        const int g = b * 256 + tid;
        int v = 0;
        if (g < NN) {
#pragma unroll
            for (int c = 0; c < 4; c++)
                v += (int)(packedAll[(size_t)c * NN + g] >> 24);
        }
        sm[tid] = v;
        __syncthreads();
#pragma unroll
        for (int off = 1; off < 256; off <<= 1) {
            int uu = (tid >= off) ? sm[tid - off] : 0;
            __syncthreads();
            sm[tid] += uu;
            __syncthreads();
        }
        locals[g] = sm[tid] - v;
        if (tid == 255) partials[b] = sm[tid];
        __syncthreads();
    }
    gridbar(bars + 2);

    // ========== p3: chunk base via tree-reduce; emit start/base4/dinv
    for (int b = bx; b < NB; b += GRID) {
        int* sm = (int*)(&As[0][0]);
        sm[tid] = (tid < b) ? partials[tid] : 0;    // b <= 195 < 256
        __syncthreads();
#pragma unroll
        for (int off = 128; off > 0; off >>= 1) {
            if (tid < off) sm[tid] += sm[tid + off];
            __syncthreads();
        }
        const int base = sm[0];
        const int g = b * 256 + tid;
        if (g < NN) {
            int cc[4];
            unsigned lowsum = 0;
#pragma unroll
            for (int c = 0; c < 4; c++) {
                unsigned p = packedAll[(size_t)c * NN + g];
                cc[c] = (int)(p >> 24);
                lowsum += p & 0xFFFFFFu;
            }
            const int s = locals[g] + base;
            start[g] = s;
            base4[g] = make_int4(s, s + cc[0], s + cc[0] + cc[1], s + cc[0] + cc[1] + cc[2]);
            float degs = (float)lowsum * (1.0f / 262144.0f);
            dinv[g] = rsqrtf(1.0f + degs);
        }
        if (g == 0) start[NN] = NE;
        __syncthreads();
    }
    gridbar(bars + 3);

    // ========== p4: atomic-free CSR placement
    for (int h = bx; h < HIST_BLOCKS; h += GRID) {
        const int e = h * 256 + tid;
        if (e < NE) {
            const int copy = h & 3;
            const int c = col[e];
            const int r = row[e];
            int4 b4 = base4[c];
            int b0 = (copy == 0) ? b4.x : (copy == 1) ? b4.y : (copy == 2) ? b4.z : b4.w;
            unsigned short wbf = f2bf(dinv[r] * ew[e]);
            meta[b0 + rank[e]] = ((unsigned)wbf << 16) | (unsigned)r;
        }
    }
    gridbar(bars + 4);

    // ========== p5: pull aggregation, one wave per node, fused epilogue
    for (int g = bx; g < NGROUP; g += GRID) {
        const int n0 = g * 4 + (tid >> 6);
        if (n0 < NN) {
            const int n = __builtin_amdgcn_readfirstlane(n0);
            const int lane = tid & 63;
            const int s = __builtin_amdgcn_readfirstlane(start[n]);
            const int e = __builtin_amdgcn_readfirstlane(start[n + 1]);

            float A0[8], A1[8];
#pragma unroll
            for (int j = 0; j < 8; j++) { A0[j] = 0.f; A1[j] = 0.f; }

            int i = s;
            for (; i + 8 <= e; i += 8) {
                unsigned m[8], uu[8];
#pragma unroll
                for (int j = 0; j < 8; j++) m[j] = meta[i + j];
#pragma unroll
                for (int j = 0; j < 8; j++)
                    uu[j] = *(const unsigned*)(hb + (size_t)(m[j] & 0xFFFFu) * CD + lane * 2);
#pragma unroll
                for (int j = 0; j < 8; j++) {
                    float w = __uint_as_float(m[j] & 0xFFFF0000u);
                    A0[j] = fmaf(w, bf2f_lo(uu[j]), A0[j]);
                    A1[j] = fmaf(w, bf2f_hi(uu[j]), A1[j]);
                }
            }
            for (; i < e; i++) {
                unsigned m = meta[i];
                unsigned uu = *(const unsigned*)(hb + (size_t)(m & 0xFFFFu) * CD + lane * 2);
                float w = __uint_as_float(m & 0xFFFF0000u);
                A0[0] = fmaf(w, bf2f_lo(uu), A0[0]);
                A1[0] = fmaf(w, bf2f_hi(uu), A1[0]);
            }
#pragma unroll
            for (int j = 1; j < 8; j++) { A0[0] += A0[j]; A1[0] += A1[j]; }

            const float dc = dinv[n];
            unsigned us = *(const unsigned*)(hb + (size_t)n * CD + lane * 2);
            const int ch = lane * 2;
            float o0 = dc * A0[0] + dc * dc * bf2f_lo(us) + bias[ch];
            float o1 = dc * A1[0] + dc * dc * bf2f_hi(us) + bias[ch + 1];
            o0 = o0 >= 0.f ? o0 : alpha[ch] * o0;
            o1 = o1 >= 0.f ? o1 : alpha[ch + 1] * o1;
            *(float2*)(out + (size_t)n * CD + ch) = make_float2(o0, o1);
        }
    }
}

extern "C" void kernel_launch(void* const* d_in, const int* in_sizes, int n_in,
                              void* d_out, int out_size, void* d_ws, size_t ws_size,
                              hipStream_t stream) {
    const float* x     = (const float*)d_in[0];
    const int*   eidx  = (const int*)d_in[1];   // [2, NE]
    const float* ew    = (const float*)d_in[2];
    const float* Wm    = (const float*)d_in[3];
    const float* bias  = (const float*)d_in[4];
    const float* alpha = (const float*)d_in[5];
    const int* row = eidx;
    const int* col = eidx + NE;

    float* out = (float*)d_out;

    // workspace layout (bytes), no overlaps:
    char* ws = (char*)d_ws;
    unsigned* packedAll = (unsigned*)(ws);                   // 4*NN u32   [0, 800000)
    int*   start    = (int*)(ws + 800000);                   // NN+1 int   [800000, 1000004)
    int*   locals   = (int*)(ws + 1000064);                  // 50176 int  [1000064, 1200768)
    int*   partials = (int*)(ws + 1200768);                  // NB int     [1200768, 1201552)
    float* dinv     = (float*)(ws + 1201552);                // NN f32     [1201552, 1401552)
    unsigned short* rank = (unsigned short*)(ws + 1401552);  // NE u16     [1401552, 3001552)
    int4*  base4    = (int4*)(ws + 3001552);                 // NN int4    [3001552, 3801552)
    unsigned* meta  = (unsigned*)(ws + 3801552);             // NE u32     [3801552, 7001552)
    unsigned short* Wt = (unsigned short*)(ws + 7001552);    // 128*256 bf16 [7001552, 7067088)
    unsigned short* hb = (unsigned short*)(ws + 7067088);    // 50176*128 bf16 [7067088, 19912144)
    unsigned* bars  = (unsigned*)(ws + 19912160);            // 5 u32 barrier counters

    hipMemsetAsync(bars, 0, 32, stream);
    mega<<<GRID, 256, 0, stream>>>(x, row, col, ew, Wm, bias, alpha, out,
                                   packedAll, start, locals, partials, dinv,
                                   rank, base4, meta, Wt, hb, bars);
}

// Round 4
// 478.572 us; speedup vs baseline: 2.1487x; 2.1487x over previous
//
#include <hip/hip_runtime.h>

#define NN 50000
#define NE 800000
#define KD 256
#define CD 128
#define NB 196            // scan chunks: 196*256 = 50176 >= NN
#define GEMM_BLOCKS 782   // (NN+63)/64 GEMM tiles
#define HIST_BLOCKS 3125  // (NE+255)/256 edge chunks
#define GRID 1280         // 5 blocks/CU x 256 CUs — one block/CU of slack
#define BPG 20            // blocks per barrier group = GRID/64
#define NGROUP 12500      // NN/4 aggregate groups (4 nodes/block-pass)
#define BAR_U32 2080      // per-barrier u32s: 64 lines x 32 + 1 root line x 32

typedef __attribute__((ext_vector_type(8))) short short8;
typedef __attribute__((ext_vector_type(4))) float floatx4;

__device__ inline unsigned short f2bf(float f) {
    unsigned u = __float_as_uint(f);
    unsigned r = (u + 0x7FFFu + ((u >> 16) & 1u)) >> 16;   // RNE
    return (unsigned short)r;
}
__device__ inline float bf2f_lo(unsigned u) { return __uint_as_float(u << 16); }
__device__ inline float bf2f_hi(unsigned u) { return __uint_as_float(u & 0xFFFF0000u); }

// Hierarchical device-scope grid barrier.
// Round 2's flat barrier cost ~150us each: 1536 same-line atomic RMWs
// serialize at ~100ns at the coherence point. Here arrivals spread over 64
// 128B lines (20 each), last-of-group RMWs one root (64-way), global last
// broadcasts a release word to each line; pollers spin on their own line.
__device__ inline void gridbar(unsigned* base, int bx) {
    __syncthreads();
    if (threadIdx.x == 0) {
        __threadfence();                          // release: writeback dirty L2
        unsigned* line = base + (bx & 63) * 32;   // 128B-spaced lines
        unsigned old = atomicAdd(line, 1u);
        if (old == (BPG - 1)) {                   // last of 20 in this group
            unsigned r = atomicAdd(base + 64 * 32, 1u);
            if (r == 63) {                        // global last: broadcast
                for (int i = 0; i < 64; i++)
                    __hip_atomic_store(base + i * 32 + 1, 1u,
                                       __ATOMIC_RELAXED, __HIP_MEMORY_SCOPE_AGENT);
            }
        }
        while (__hip_atomic_load(line + 1, __ATOMIC_RELAXED,
                                 __HIP_MEMORY_SCOPE_AGENT) == 0)
            __builtin_amdgcn_s_sleep(4);          // ~256 cy backoff
        __threadfence();                          // acquire: invalidate stale
    }
    __syncthreads();
}

__global__ __launch_bounds__(256, 5) void mega(
        const float* __restrict__ x, const int* __restrict__ row,
        const int* __restrict__ col, const float* __restrict__ ew,
        const float* __restrict__ W, const float* __restrict__ bias,
        const float* __restrict__ alpha, float* __restrict__ out,
        unsigned* __restrict__ packedAll, int* __restrict__ start,
        int* __restrict__ locals, int* __restrict__ partials,
        float* __restrict__ dinv, unsigned short* __restrict__ rank,
        int4* __restrict__ base4, unsigned* __restrict__ meta,
        unsigned short* __restrict__ Wt, unsigned short* __restrict__ hb,
        unsigned* __restrict__ bars) {
    __shared__ unsigned short As[64][40];
    __shared__ unsigned short Bs[128][40];
    const int tid = threadIdx.x;
    const int bx  = blockIdx.x;

    // ========== p0: zero histogram shadows (blocks 0..781) + W transpose
    // (last 32 blocks, aliasing As as a 32x33 tile)
    {
        const int z = bx * 256 + tid;
        if (z < 4 * NN) packedAll[z] = 0u;
    }
    if (bx >= GRID - 32) {
        unsigned short (*t)[33] = (unsigned short (*)[33])(&As[0][0]);
        const int b2 = bx - (GRID - 32);       // [0,32): 8 k-tiles x 4 n-tiles
        const int bk = (b2 & 7) * 32;
        const int bn = (b2 >> 3) * 32;
        const int tx = tid & 31;
        const int ty = tid >> 5;
#pragma unroll
        for (int i = 0; i < 32; i += 8)
            t[ty + i][tx] = f2bf(W[(size_t)(bk + ty + i) * CD + bn + tx]);
        __syncthreads();
#pragma unroll
        for (int i = 0; i < 32; i += 8)
            Wt[(size_t)(bn + ty + i) * KD + bk + tx] = t[tx][ty + i];
    }
    gridbar(bars + 0 * BAR_U32, bx);

    // ========== p1: GEMM tiles (units 0..781) + hist chunks (rest), mixed
    // grid-stride so GEMM starts immediately on blocks 0..781 and hist's
    // atomic latency hides under the MFMA work.
    for (int u = bx; u < GEMM_BLOCKS + HIST_BLOCKS; u += GRID) {
        if (u < GEMM_BLOCKS) {
            const int wave = tid >> 6;
            const int lane = tid & 63;
            const int row0 = u * 64;
            const int m0   = wave * 16;
            const int lr   = lane & 15;
            const int quad = lane >> 4;
            const int ar = tid >> 2;
            const int aq = tid & 3;
            const int bn = tid >> 1;
            const int bh = (tid & 1) * 16;

            const int gr = row0 + ar;
            const bool ok = gr < NN;
            const float* xb = x + (size_t)gr * KD + aq * 8;
            const unsigned short* wb = Wt + (size_t)bn * KD + bh;

            floatx4 acc[8];
#pragma unroll
            for (int nt = 0; nt < 8; nt++) acc[nt] = (floatx4){0.f, 0.f, 0.f, 0.f};

            float4 f0 = {0.f,0.f,0.f,0.f}, f1 = {0.f,0.f,0.f,0.f};
            short8 wv0, wv1;
            if (ok) { f0 = *(const float4*)xb; f1 = *(const float4*)(xb + 4); }
            wv0 = *(const short8*)wb;
            wv1 = *(const short8*)(wb + 8);

#pragma unroll
            for (int kt = 0; kt < 8; kt++) {
                union { short8 v; unsigned short us[8]; } av;
                if (ok) {
                    av.us[0] = f2bf(f0.x); av.us[1] = f2bf(f0.y);
                    av.us[2] = f2bf(f0.z); av.us[3] = f2bf(f0.w);
                    av.us[4] = f2bf(f1.x); av.us[5] = f2bf(f1.y);
                    av.us[6] = f2bf(f1.z); av.us[7] = f2bf(f1.w);
                } else {
                    av.v = (short8){0,0,0,0,0,0,0,0};
                }
                *(short8*)&As[ar][aq * 8] = av.v;
                *(short8*)&Bs[bn][bh]     = wv0;
                *(short8*)&Bs[bn][bh + 8] = wv1;
                __syncthreads();
                if (kt < 7) {
                    const float* xp = xb + (kt + 1) * 32;
                    if (ok) { f0 = *(const float4*)xp; f1 = *(const float4*)(xp + 4); }
                    const unsigned short* wp = wb + (kt + 1) * 32;
                    wv0 = *(const short8*)wp;
                    wv1 = *(const short8*)(wp + 8);
                }
                short8 af = *(const short8*)&As[m0 + lr][quad * 8];
#pragma unroll
                for (int nt = 0; nt < 8; nt++) {
                    short8 bfr = *(const short8*)&Bs[nt * 16 + lr][quad * 8];
                    acc[nt] = __builtin_amdgcn_mfma_f32_16x16x32_bf16(af, bfr, acc[nt], 0, 0, 0);
                }
                __syncthreads();
            }
#pragma unroll
            for (int i = 0; i < 4; i++) {
                const int grow = row0 + m0 + quad * 4 + i;
                if (grow < NN) {
                    unsigned short* hp = hb + (size_t)grow * CD + lr;
#pragma unroll
                    for (int nt = 0; nt < 8; nt++)
                        hp[nt * 16] = f2bf(acc[nt][i]);
                }
            }
        } else {
            // hist: u32 packed {count:8 | sum(ew) Q6.18:24}, 4 shadow copies,
            // copy = chunk&3 == (e>>8)&3 (matches p4's formula)
            const int h = u - GEMM_BLOCKS;
            const int e = h * 256 + tid;
            if (e < NE) {
                unsigned* packed = packedAll + (size_t)(h & 3) * NN;
                unsigned p = (1u << 24) + (unsigned)(ew[e] * 262144.0f);
                unsigned old = atomicAdd(&packed[col[e]], p);
                rank[e] = (unsigned short)(old >> 24);
            }
        }
    }
    gridbar(bars + 1 * BAR_U32, bx);

    // ========== p2: per-chunk exclusive scan of counts (196 chunks)
    for (int b = bx; b < NB; b += GRID) {
        int* sm = (int*)(&As[0][0]);
        const int g = b * 256 + tid;
        int v = 0;
        if (g < NN) {
#pragma unroll
            for (int c = 0; c < 4; c++)
                v += (int)(packedAll[(size_t)c * NN + g] >> 24);
        }
        sm[tid] = v;
        __syncthreads();
#pragma unroll
        for (int off = 1; off < 256; off <<= 1) {
            int uu = (tid >= off) ? sm[tid - off] : 0;
            __syncthreads();
            sm[tid] += uu;
            __syncthreads();
        }
        locals[g] = sm[tid] - v;
        if (tid == 255) partials[b] = sm[tid];
        __syncthreads();
    }
    gridbar(bars + 2 * BAR_U32, bx);

    // ========== p3: chunk base via tree-reduce; emit start/base4/dinv
    for (int b = bx; b < NB; b += GRID) {
        int* sm = (int*)(&As[0][0]);
        sm[tid] = (tid < b) ? partials[tid] : 0;    // b <= 195 < 256
        __syncthreads();
#pragma unroll
        for (int off = 128; off > 0; off >>= 1) {
            if (tid < off) sm[tid] += sm[tid + off];
            __syncthreads();
        }
        const int base = sm[0];
        const int g = b * 256 + tid;
        if (g < NN) {
            int cc[4];
            unsigned lowsum = 0;
#pragma unroll
            for (int c = 0; c < 4; c++) {
                unsigned p = packedAll[(size_t)c * NN + g];
                cc[c] = (int)(p >> 24);
                lowsum += p & 0xFFFFFFu;
            }
            const int s = locals[g] + base;
            start[g] = s;
            base4[g] = make_int4(s, s + cc[0], s + cc[0] + cc[1], s + cc[0] + cc[1] + cc[2]);
            float degs = (float)lowsum * (1.0f / 262144.0f);
            dinv[g] = rsqrtf(1.0f + degs);
        }
        if (g == 0) start[NN] = NE;
        __syncthreads();
    }
    gridbar(bars + 3 * BAR_U32, bx);

    // ========== p4: atomic-free CSR placement
    for (int h = bx; h < HIST_BLOCKS; h += GRID) {
        const int e = h * 256 + tid;
        if (e < NE) {
            const int copy = h & 3;
            const int c = col[e];
            const int r = row[e];
            int4 b4 = base4[c];
            int b0 = (copy == 0) ? b4.x : (copy == 1) ? b4.y : (copy == 2) ? b4.z : b4.w;
            unsigned short wbf = f2bf(dinv[r] * ew[e]);
            meta[b0 + rank[e]] = ((unsigned)wbf << 16) | (unsigned)r;
        }
    }
    gridbar(bars + 4 * BAR_U32, bx);

    // ========== p5: pull aggregation, one wave per node, fused epilogue
    for (int g = bx; g < NGROUP; g += GRID) {
        const int n0 = g * 4 + (tid >> 6);
        if (n0 < NN) {
            const int n = __builtin_amdgcn_readfirstlane(n0);
            const int lane = tid & 63;
            const int s = __builtin_amdgcn_readfirstlane(start[n]);
            const int e = __builtin_amdgcn_readfirstlane(start[n + 1]);

            float A0[8], A1[8];
#pragma unroll
            for (int j = 0; j < 8; j++) { A0[j] = 0.f; A1[j] = 0.f; }

            int i = s;
            for (; i + 8 <= e; i += 8) {
                unsigned m[8], uu[8];
#pragma unroll
                for (int j = 0; j < 8; j++) m[j] = meta[i + j];
#pragma unroll
                for (int j = 0; j < 8; j++)
                    uu[j] = *(const unsigned*)(hb + (size_t)(m[j] & 0xFFFFu) * CD + lane * 2);
#pragma unroll
                for (int j = 0; j < 8; j++) {
                    float w = __uint_as_float(m[j] & 0xFFFF0000u);
                    A0[j] = fmaf(w, bf2f_lo(uu[j]), A0[j]);
                    A1[j] = fmaf(w, bf2f_hi(uu[j]), A1[j]);
                }
            }
            for (; i < e; i++) {
                unsigned m = meta[i];
                unsigned uu = *(const unsigned*)(hb + (size_t)(m & 0xFFFFu) * CD + lane * 2);
                float w = __uint_as_float(m & 0xFFFF0000u);
                A0[0] = fmaf(w, bf2f_lo(uu), A0[0]);
                A1[0] = fmaf(w, bf2f_hi(uu), A1[0]);
            }
#pragma unroll
            for (int j = 1; j < 8; j++) { A0[0] += A0[j]; A1[0] += A1[j]; }

            const float dc = dinv[n];
            unsigned us = *(const unsigned*)(hb + (size_t)n * CD + lane * 2);
            const int ch = lane * 2;
            float o0 = dc * A0[0] + dc * dc * bf2f_lo(us) + bias[ch];
            float o1 = dc * A1[0] + dc * dc * bf2f_hi(us) + bias[ch + 1];
            o0 = o0 >= 0.f ? o0 : alpha[ch] * o0;
            o1 = o1 >= 0.f ? o1 : alpha[ch + 1] * o1;
            *(float2*)(out + (size_t)n * CD + ch) = make_float2(o0, o1);
        }
    }
}

extern "C" void kernel_launch(void* const* d_in, const int* in_sizes, int n_in,
                              void* d_out, int out_size, void* d_ws, size_t ws_size,
                              hipStream_t stream) {
    const float* x     = (const float*)d_in[0];
    const int*   eidx  = (const int*)d_in[1];   // [2, NE]
    const float* ew    = (const float*)d_in[2];
    const float* Wm    = (const float*)d_in[3];
    const float* bias  = (const float*)d_in[4];
    const float* alpha = (const float*)d_in[5];
    const int* row = eidx;
    const int* col = eidx + NE;

    float* out = (float*)d_out;

    // workspace layout (bytes), no overlaps (ends at ~19.95 MB; the original
    // session's proven footprint was 20.7 MB, so ws_size covers it):
    char* ws = (char*)d_ws;
    unsigned* packedAll = (unsigned*)(ws);                   // 4*NN u32   [0, 800000)
    int*   start    = (int*)(ws + 800000);                   // NN+1 int   [800000, 1000004)
    int*   locals   = (int*)(ws + 1000064);                  // 50176 int  [1000064, 1200768)
    int*   partials = (int*)(ws + 1200768);                  // NB int     [1200768, 1201552)
    float* dinv     = (float*)(ws + 1201552);                // NN f32     [1201552, 1401552)
    unsigned short* rank = (unsigned short*)(ws + 1401552);  // NE u16     [1401552, 3001552)
    int4*  base4    = (int4*)(ws + 3001552);                 // NN int4    [3001552, 3801552)
    unsigned* meta  = (unsigned*)(ws + 3801552);             // NE u32     [3801552, 7001552)
    unsigned short* Wt = (unsigned short*)(ws + 7001552);    // 128*256 bf16 [7001552, 7067088)
    unsigned short* hb = (unsigned short*)(ws + 7067088);    // 50176*128 bf16 [7067088, 19912144)
    unsigned* bars  = (unsigned*)(ws + 19912192);            // 5 * 2080 u32 barrier state

    hipMemsetAsync(bars, 0, 5 * BAR_U32 * 4, stream);
    mega<<<GRID, 256, 0, stream>>>(x, row, col, ew, Wm, bias, alpha, out,
                                   packedAll, start, locals, partials, dinv,
                                   rank, base4, meta, Wt, hb, bars);
}

// Round 5
// 193.622 us; speedup vs baseline: 5.3109x; 2.4717x over previous
//
#include <hip/hip_runtime.h>

#define NN 50000
#define NE 800000
#define KD 256
#define CD 128
#define NB 196            // scan blocks: 196*256 = 50176 >= NN
#define GEMM_BLOCKS 782   // (NN+63)/64
#define HIST_BLOCKS 3125  // (NE+255)/256

typedef __attribute__((ext_vector_type(8))) short short8;
typedef __attribute__((ext_vector_type(4))) float floatx4;

__device__ inline unsigned short f2bf(float f) {
    unsigned u = __float_as_uint(f);
    unsigned r = (u + 0x7FFFu + ((u >> 16) & 1u)) >> 16;   // RNE
    return (unsigned short)r;
}
__device__ inline float bf2f_lo(unsigned u) { return __uint_as_float(u << 16); }
__device__ inline float bf2f_hi(unsigned u) { return __uint_as_float(u & 0xFFFF0000u); }

// ===== prep: zero u32 histogram shadows + scan state (blocks < NB),
// W transpose (last 32 blocks) =====
__global__ __launch_bounds__(256) void prep(const float* __restrict__ W,
                                            unsigned short* __restrict__ Wt,
                                            unsigned* __restrict__ packedAll,
                                            unsigned long long* __restrict__ state) {
    __shared__ unsigned short t[32][33];
    if (blockIdx.x < NB) {
        const int g = blockIdx.x * 256 + threadIdx.x;
        if (g < NN) {
#pragma unroll
            for (int c = 0; c < 4; c++) packedAll[(size_t)c * NN + g] = 0u;
        }
        if (blockIdx.x == 0) {
            for (int i = threadIdx.x; i < NB * 8; i += 256) state[i] = 0ull;
        }
        return;
    }
    const int b2 = blockIdx.x - NB;          // [0,32): 8 k-tiles x 4 n-tiles
    const int bk = (b2 & 7) * 32;
    const int bn = (b2 >> 3) * 32;
    const int tx = threadIdx.x & 31;
    const int ty = threadIdx.x >> 5;
#pragma unroll
    for (int i = 0; i < 32; i += 8)
        t[ty + i][tx] = f2bf(W[(size_t)(bk + ty + i) * CD + bn + tx]);
    __syncthreads();
#pragma unroll
    for (int i = 0; i < 32; i += 8)
        Wt[(size_t)(bn + ty + i) * KD + bk + tx] = t[tx][ty + i];
}

// ===== fused: GEMM tiles (blocks < GEMM_BLOCKS) + u32 histogram (rest) =====
// hist: packed {count:8 | sum(ew) Q6.18:24}, 4 shadow copies (copy = hblk&3
// == (e>>8)&3). count/copy <= ~20, sum < 64 -> no overflow; deg err 2^-18.
__global__ __launch_bounds__(256) void fused_gemm_hist(
        const float* __restrict__ x, const unsigned short* __restrict__ Wt,
        unsigned short* __restrict__ hb,
        const int* __restrict__ col, const float* __restrict__ ew,
        unsigned* __restrict__ packedAll, unsigned short* __restrict__ rank) {
    __shared__ unsigned short As[64][40];
    __shared__ unsigned short Bs[128][40];

    if (blockIdx.x >= GEMM_BLOCKS) {
        const int hblk = blockIdx.x - GEMM_BLOCKS;
        const int e = hblk * 256 + threadIdx.x;
        if (e < NE) {
            unsigned* packed = packedAll + (size_t)(hblk & 3) * NN;
            unsigned p = (1u << 24) + (unsigned)(ew[e] * 262144.0f);
            unsigned old = atomicAdd(&packed[col[e]], p);
            rank[e] = (unsigned short)(old >> 24);   // rank within copy
        }
        return;
    }

    // ---------------- GEMM role: h = bf16(x) @ Wt^T, 64 rows x 128 ch / block
    const int tid  = threadIdx.x;
    const int wave = tid >> 6;
    const int lane = tid & 63;
    const int row0 = blockIdx.x * 64;
    const int m0   = wave * 16;
    const int lr   = lane & 15;
    const int quad = lane >> 4;

    const int ar = tid >> 2;
    const int aq = tid & 3;
    const int bn = tid >> 1;
    const int bh = (tid & 1) * 16;

    const int gr = row0 + ar;
    const bool ok = gr < NN;
    const float* xb = x + (size_t)gr * KD + aq * 8;
    const unsigned short* wb = Wt + (size_t)bn * KD + bh;

    floatx4 acc[8];
#pragma unroll
    for (int nt = 0; nt < 8; nt++) acc[nt] = (floatx4){0.f, 0.f, 0.f, 0.f};

    // register double-buffer: tile kt+1 global loads overlap MFMA on tile kt
    float4 f0 = {0.f, 0.f, 0.f, 0.f}, f1 = {0.f, 0.f, 0.f, 0.f};
    short8 wv0, wv1;
    if (ok) { f0 = *(const float4*)xb; f1 = *(const float4*)(xb + 4); }
    wv0 = *(const short8*)wb;
    wv1 = *(const short8*)(wb + 8);

#pragma unroll
    for (int kt = 0; kt < 8; kt++) {
        union { short8 v; unsigned short us[8]; } av;
        if (ok) {
            av.us[0] = f2bf(f0.x); av.us[1] = f2bf(f0.y);
            av.us[2] = f2bf(f0.z); av.us[3] = f2bf(f0.w);
            av.us[4] = f2bf(f1.x); av.us[5] = f2bf(f1.y);
            av.us[6] = f2bf(f1.z); av.us[7] = f2bf(f1.w);
        } else {
            av.v = (short8){0,0,0,0,0,0,0,0};
        }
        *(short8*)&As[ar][aq * 8] = av.v;
        *(short8*)&Bs[bn][bh]     = wv0;
        *(short8*)&Bs[bn][bh + 8] = wv1;
        __syncthreads();
        if (kt < 7) {
            const float* xp = xb + (kt + 1) * 32;
            if (ok) { f0 = *(const float4*)xp; f1 = *(const float4*)(xp + 4); }
            const unsigned short* wp = wb + (kt + 1) * 32;
            wv0 = *(const short8*)wp;
            wv1 = *(const short8*)(wp + 8);
        }
        short8 af = *(const short8*)&As[m0 + lr][quad * 8];
#pragma unroll
        for (int nt = 0; nt < 8; nt++) {
            short8 bfr = *(const short8*)&Bs[nt * 16 + lr][quad * 8];
            acc[nt] = __builtin_amdgcn_mfma_f32_16x16x32_bf16(af, bfr, acc[nt], 0, 0, 0);
        }
        __syncthreads();
    }

#pragma unroll
    for (int i = 0; i < 4; i++) {
        const int grow = row0 + m0 + quad * 4 + i;
        if (grow < NN) {
            unsigned short* hp = hb + (size_t)grow * CD + lr;
#pragma unroll
            for (int nt = 0; nt < 8; nt++)
                hp[nt * 16] = f2bf(acc[nt][i]);
        }
    }
}

// ===== single-launch scan via decoupled lookback =====
// state[b*8] u64 = {status:32 | value:32}; status 0=invalid, 1=aggregate,
// 2=inclusive prefix. Flag+value travel in ONE relaxed agent-scope atomic
// (the cross-XCD pattern rounds 2/4 verified), so no fences are needed.
// All 196 blocks are co-resident (196 < 256 CUs) -> no scheduling deadlock.
__global__ __launch_bounds__(256) void scan_lookback(
        const unsigned* __restrict__ packedAll,
        unsigned long long* __restrict__ state,
        int* __restrict__ start, int4* __restrict__ base4,
        float* __restrict__ dinv) {
    __shared__ int sm[256];
    __shared__ int sbase;
    const int t = threadIdx.x;
    const int b = blockIdx.x;
    const int g = b * 256 + t;

    int cc[4] = {0, 0, 0, 0};
    unsigned lowsum = 0;
    int v = 0;
    if (g < NN) {
#pragma unroll
        for (int c = 0; c < 4; c++) {
            unsigned p = packedAll[(size_t)c * NN + g];
            cc[c] = (int)(p >> 24);
            lowsum += p & 0xFFFFFFu;
            v += cc[c];
        }
    }
    sm[t] = v;
    __syncthreads();
#pragma unroll
    for (int off = 1; off < 256; off <<= 1) {
        int u = (t >= off) ? sm[t - off] : 0;
        __syncthreads();
        sm[t] += u;
        __syncthreads();
    }
    const int incl = sm[t];          // inclusive prefix within block
    const int total = sm[255];

    if (t == 0) {
        if (b == 0) {
            __hip_atomic_store(&state[0], (2ull << 32) | (unsigned)total,
                               __ATOMIC_RELAXED, __HIP_MEMORY_SCOPE_AGENT);
            sbase = 0;
        } else {
            __hip_atomic_store(&state[(size_t)b * 8], (1ull << 32) | (unsigned)total,
                               __ATOMIC_RELAXED, __HIP_MEMORY_SCOPE_AGENT);
            long long run = 0;
            int i = b - 1;
            while (true) {
                unsigned long long s = __hip_atomic_load(&state[(size_t)i * 8],
                                        __ATOMIC_RELAXED, __HIP_MEMORY_SCOPE_AGENT);
                unsigned st = (unsigned)(s >> 32);
                if (st == 0u) { __builtin_amdgcn_s_sleep(1); continue; }
                run += (unsigned)s;
                if (st == 2u) break;
                i--;
            }
            __hip_atomic_store(&state[(size_t)b * 8],
                               (2ull << 32) | (unsigned)(run + total),
                               __ATOMIC_RELAXED, __HIP_MEMORY_SCOPE_AGENT);
            sbase = (int)run;
        }
    }
    __syncthreads();
    const int base = sbase;

    if (g < NN) {
        const int s = base + (incl - v);
        start[g] = s;
        base4[g] = make_int4(s, s + cc[0], s + cc[0] + cc[1], s + cc[0] + cc[1] + cc[2]);
        float degs = (float)lowsum * (1.0f / 262144.0f);
        dinv[g] = rsqrtf(1.0f + degs);
    }
    if (g == 0) start[NN] = NE;
}

// -------- atomic-free CSR placement: meta[base4[col][copy]+rank] = {bf16 w | u16 row}
__global__ __launch_bounds__(256) void meta_write(const int* __restrict__ row,
                                                  const int* __restrict__ col,
                                                  const float* __restrict__ ew,
                                                  const unsigned short* __restrict__ rank,
                                                  const int4* __restrict__ base4,
                                                  const float* __restrict__ dinv,
                                                  unsigned* __restrict__ meta) {
    const int e = blockIdx.x * 256 + threadIdx.x;
    if (e >= NE) return;
    const int copy = blockIdx.x & 3;            // == (e>>8)&3, wave-uniform
    const int c = col[e];
    const int r = row[e];
    int4 b4 = base4[c];
    int base = (copy == 0) ? b4.x : (copy == 1) ? b4.y : (copy == 2) ? b4.z : b4.w;
    int pos = base + rank[e];
    unsigned short wbf = f2bf(dinv[r] * ew[e]);
    meta[pos] = ((unsigned)wbf << 16) | (unsigned)r;
}

// ---------- pull aggregation: one wave per node, bf16 h, 8-way ILP, fused epilogue
__global__ __launch_bounds__(256) void aggregate(const int* __restrict__ start,
                                                 const unsigned* __restrict__ meta,
                                                 const unsigned short* __restrict__ hb,
                                                 const float* __restrict__ dinv,
                                                 const float* __restrict__ bias,
                                                 const float* __restrict__ alpha,
                                                 float* __restrict__ out) {
    int n = blockIdx.x * 4 + (threadIdx.x >> 6);
    if (n >= NN) return;
    n = __builtin_amdgcn_readfirstlane(n);
    const int lane = threadIdx.x & 63;
    const int s = __builtin_amdgcn_readfirstlane(start[n]);
    const int e = __builtin_amdgcn_readfirstlane(start[n + 1]);

    float A0[8], A1[8];
#pragma unroll
    for (int j = 0; j < 8; j++) { A0[j] = 0.f; A1[j] = 0.f; }

    int i = s;
    for (; i + 8 <= e; i += 8) {
        unsigned m[8], u[8];
#pragma unroll
        for (int j = 0; j < 8; j++) m[j] = meta[i + j];
#pragma unroll
        for (int j = 0; j < 8; j++)
            u[j] = *(const unsigned*)(hb + (size_t)(m[j] & 0xFFFFu) * CD + lane * 2);
#pragma unroll
        for (int j = 0; j < 8; j++) {
            float w = __uint_as_float(m[j] & 0xFFFF0000u);
            A0[j] = fmaf(w, bf2f_lo(u[j]), A0[j]);
            A1[j] = fmaf(w, bf2f_hi(u[j]), A1[j]);
        }
    }
    for (; i < e; i++) {
        unsigned m = meta[i];
        unsigned u = *(const unsigned*)(hb + (size_t)(m & 0xFFFFu) * CD + lane * 2);
        float w = __uint_as_float(m & 0xFFFF0000u);
        A0[0] = fmaf(w, bf2f_lo(u), A0[0]);
        A1[0] = fmaf(w, bf2f_hi(u), A1[0]);
    }
#pragma unroll
    for (int j = 1; j < 8; j++) { A0[0] += A0[j]; A1[0] += A1[j]; }

    const float dc = dinv[n];
    unsigned us = *(const unsigned*)(hb + (size_t)n * CD + lane * 2);
    const int ch = lane * 2;
    float o0 = dc * A0[0] + dc * dc * bf2f_lo(us) + bias[ch];
    float o1 = dc * A1[0] + dc * dc * bf2f_hi(us) + bias[ch + 1];
    o0 = o0 >= 0.f ? o0 : alpha[ch] * o0;
    o1 = o1 >= 0.f ? o1 : alpha[ch + 1] * o1;
    *(float2*)(out + (size_t)n * CD + ch) = make_float2(o0, o1);
}

extern "C" void kernel_launch(void* const* d_in, const int* in_sizes, int n_in,
                              void* d_out, int out_size, void* d_ws, size_t ws_size,
                              hipStream_t stream) {
    const float* x     = (const float*)d_in[0];
    const int*   eidx  = (const int*)d_in[1];   // [2, NE]
    const float* ew    = (const float*)d_in[2];
    const float* Wm    = (const float*)d_in[3];
    const float* bias  = (const float*)d_in[4];
    const float* alpha = (const float*)d_in[5];
    const int* row = eidx;
    const int* col = eidx + NE;

    float* out = (float*)d_out;

    // workspace layout (bytes), no overlaps:
    char* ws = (char*)d_ws;
    unsigned* packedAll = (unsigned*)(ws);                   // 4*NN u32   [0, 800000)
    int*   start    = (int*)(ws + 800000);                   // NN+1 int   [800000, 1000004)
    float* dinv     = (float*)(ws + 1000064);                // NN f32     [1000064, 1200064)
    unsigned short* rank = (unsigned short*)(ws + 1200064);  // NE u16     [1200064, 2800064)
    int4*  base4    = (int4*)(ws + 2800064);                 // NN int4    [2800064, 3600064)
    unsigned* meta  = (unsigned*)(ws + 3600064);             // NE u32     [3600064, 6800064)
    unsigned short* Wt = (unsigned short*)(ws + 6800064);    // 128*256 bf16 [6800064, 6865600)
    unsigned long long* state = (unsigned long long*)(ws + 6865600); // NB*8 u64 [6865600, 6878144)
    unsigned short* hb = (unsigned short*)(ws + 6878208);    // 50176*128 bf16 [6878208, 19723264)

    prep          <<<NB + 32, 256, 0, stream>>>(Wm, Wt, packedAll, state);
    fused_gemm_hist<<<GEMM_BLOCKS + HIST_BLOCKS, 256, 0, stream>>>(
                        x, Wt, hb, col, ew, packedAll, rank);
    scan_lookback <<<NB, 256, 0, stream>>>(packedAll, state, start, base4, dinv);
    meta_write    <<<HIST_BLOCKS, 256, 0, stream>>>(row, col, ew, rank, base4, dinv, meta);
    aggregate     <<<(NN + 3) / 4, 256, 0, stream>>>(start, meta, hb, dinv, bias, alpha, out);
}

// Round 7
// 186.168 us; speedup vs baseline: 5.5235x; 1.0400x over previous
//
#include <hip/hip_runtime.h>

#define NN 50000
#define NE 800000
#define KD 256
#define CD 128
#define NB 196            // scan blocks: 196*256 = 50176 >= NN
#define GEMM_BLOCKS 782   // (NN+63)/64
#define HIST_BLOCKS 3125  // (NE+255)/256
#define META_BLOCKS 782   // 800000 edges / (256 thr * 4 edges) = 781.25

typedef __attribute__((ext_vector_type(8))) short short8;
typedef __attribute__((ext_vector_type(4))) float floatx4;
typedef __attribute__((ext_vector_type(2))) float floatx2;

__device__ inline unsigned short f2bf(float f) {
    unsigned u = __float_as_uint(f);
    unsigned r = (u + 0x7FFFu + ((u >> 16) & 1u)) >> 16;   // RNE
    return (unsigned short)r;
}
__device__ inline float bf2f_lo(unsigned u) { return __uint_as_float(u << 16); }
__device__ inline float bf2f_hi(unsigned u) { return __uint_as_float(u & 0xFFFF0000u); }

// ===== prep: zero u32 histogram shadows + scan state (blocks < NB),
// W transpose (last 32 blocks) =====
__global__ __launch_bounds__(256) void prep(const float* __restrict__ W,
                                            unsigned short* __restrict__ Wt,
                                            unsigned* __restrict__ packedAll,
                                            unsigned long long* __restrict__ state) {
    __shared__ unsigned short t[32][33];
    if (blockIdx.x < NB) {
        const int g = blockIdx.x * 256 + threadIdx.x;
        if (g < NN) {
#pragma unroll
            for (int c = 0; c < 4; c++) packedAll[(size_t)c * NN + g] = 0u;
        }
        if (blockIdx.x == 0) {
            for (int i = threadIdx.x; i < NB * 8; i += 256) state[i] = 0ull;
        }
        return;
    }
    const int b2 = blockIdx.x - NB;          // [0,32): 8 k-tiles x 4 n-tiles
    const int bk = (b2 & 7) * 32;
    const int bn = (b2 >> 3) * 32;
    const int tx = threadIdx.x & 31;
    const int ty = threadIdx.x >> 5;
#pragma unroll
    for (int i = 0; i < 32; i += 8)
        t[ty + i][tx] = f2bf(W[(size_t)(bk + ty + i) * CD + bn + tx]);
    __syncthreads();
#pragma unroll
    for (int i = 0; i < 32; i += 8)
        Wt[(size_t)(bn + ty + i) * KD + bk + tx] = t[tx][ty + i];
}

// ===== fused: GEMM tiles (blocks < GEMM_BLOCKS) + u32 histogram (rest) =====
// hist: packed {count:8 | sum(ew) Q6.18:24}, 4 shadow copies (copy = hblk&3
// == (e>>8)&3). count/copy <= ~20, sum < 64 -> no overflow; deg err 2^-18.
__global__ __launch_bounds__(256) void fused_gemm_hist(
        const float* __restrict__ x, const unsigned short* __restrict__ Wt,
        unsigned short* __restrict__ hb,
        const int* __restrict__ col, const float* __restrict__ ew,
        unsigned* __restrict__ packedAll, unsigned short* __restrict__ rank) {
    __shared__ unsigned short As[64][40];
    __shared__ unsigned short Bs[128][40];

    if (blockIdx.x >= GEMM_BLOCKS) {
        const int hblk = blockIdx.x - GEMM_BLOCKS;
        const int e = hblk * 256 + threadIdx.x;
        if (e < NE) {
            unsigned* packed = packedAll + (size_t)(hblk & 3) * NN;
            unsigned p = (1u << 24) + (unsigned)(ew[e] * 262144.0f);
            unsigned old = atomicAdd(&packed[col[e]], p);
            rank[e] = (unsigned short)(old >> 24);   // rank within copy
        }
        return;
    }

    // ---------------- GEMM role: h = bf16(x) @ Wt^T, 64 rows x 128 ch / block
    const int tid  = threadIdx.x;
    const int wave = tid >> 6;
    const int lane = tid & 63;
    const int row0 = blockIdx.x * 64;
    const int m0   = wave * 16;
    const int lr   = lane & 15;
    const int quad = lane >> 4;

    const int ar = tid >> 2;
    const int aq = tid & 3;
    const int bn = tid >> 1;
    const int bh = (tid & 1) * 16;

    const int gr = row0 + ar;
    const bool ok = gr < NN;
    const float* xb = x + (size_t)gr * KD + aq * 8;
    const unsigned short* wb = Wt + (size_t)bn * KD + bh;

    floatx4 acc[8];
#pragma unroll
    for (int nt = 0; nt < 8; nt++) acc[nt] = (floatx4){0.f, 0.f, 0.f, 0.f};

    // register double-buffer: tile kt+1 global loads overlap MFMA on tile kt
    float4 f0 = {0.f, 0.f, 0.f, 0.f}, f1 = {0.f, 0.f, 0.f, 0.f};
    short8 wv0, wv1;
    if (ok) { f0 = *(const float4*)xb; f1 = *(const float4*)(xb + 4); }
    wv0 = *(const short8*)wb;
    wv1 = *(const short8*)(wb + 8);

#pragma unroll
    for (int kt = 0; kt < 8; kt++) {
        union { short8 v; unsigned short us[8]; } av;
        if (ok) {
            av.us[0] = f2bf(f0.x); av.us[1] = f2bf(f0.y);
            av.us[2] = f2bf(f0.z); av.us[3] = f2bf(f0.w);
            av.us[4] = f2bf(f1.x); av.us[5] = f2bf(f1.y);
            av.us[6] = f2bf(f1.z); av.us[7] = f2bf(f1.w);
        } else {
            av.v = (short8){0,0,0,0,0,0,0,0};
        }
        *(short8*)&As[ar][aq * 8] = av.v;
        *(short8*)&Bs[bn][bh]     = wv0;
        *(short8*)&Bs[bn][bh + 8] = wv1;
        __syncthreads();
        if (kt < 7) {
            const float* xp = xb + (kt + 1) * 32;
            if (ok) { f0 = *(const float4*)xp; f1 = *(const float4*)(xp + 4); }
            const unsigned short* wp = wb + (kt + 1) * 32;
            wv0 = *(const short8*)wp;
            wv1 = *(const short8*)(wp + 8);
        }
        short8 af = *(const short8*)&As[m0 + lr][quad * 8];
#pragma unroll
        for (int nt = 0; nt < 8; nt++) {
            short8 bfr = *(const short8*)&Bs[nt * 16 + lr][quad * 8];
            acc[nt] = __builtin_amdgcn_mfma_f32_16x16x32_bf16(af, bfr, acc[nt], 0, 0, 0);
        }
        __syncthreads();
    }

#pragma unroll
    for (int i = 0; i < 4; i++) {
        const int grow = row0 + m0 + quad * 4 + i;
        if (grow < NN) {
            unsigned short* hp = hb + (size_t)grow * CD + lr;
#pragma unroll
            for (int nt = 0; nt < 8; nt++)
                hp[nt * 16] = f2bf(acc[nt][i]);
        }
    }
}

// ===== single-launch scan, WAVE-PARALLEL decoupled lookback =====
// state[b*8] u64 = {status:32 | value:32}; 0=invalid, 1=aggregate, 2=prefix.
// Flag+value travel in one relaxed agent-scope word (cross-XCD-safe pattern).
// Lookback reads 64 predecessors per round: lane t reads state[i-t]; ballot
// finds the lowest-lane status-2 (= highest block with full prefix); wave-
// reduce sums the covered aggregates. Critical path ~ceil(b/64) rounds, not b.
__global__ __launch_bounds__(256) void scan_lookback(
        const unsigned* __restrict__ packedAll,
        unsigned long long* __restrict__ state,
        int* __restrict__ start, int4* __restrict__ base4,
        float* __restrict__ dinv) {
    __shared__ int sm[256];
    __shared__ int sbase;
    const int t = threadIdx.x;
    const int b = blockIdx.x;
    const int g = b * 256 + t;

    int cc[4] = {0, 0, 0, 0};
    unsigned lowsum = 0;
    int v = 0;
    if (g < NN) {
#pragma unroll
        for (int c = 0; c < 4; c++) {
            unsigned p = packedAll[(size_t)c * NN + g];
            cc[c] = (int)(p >> 24);
            lowsum += p & 0xFFFFFFu;
            v += cc[c];
        }
    }
    sm[t] = v;
    __syncthreads();
#pragma unroll
    for (int off = 1; off < 256; off <<= 1) {
        int u = (t >= off) ? sm[t - off] : 0;
        __syncthreads();
        sm[t] += u;
        __syncthreads();
    }
    const int incl = sm[t];          // inclusive prefix within block
    const int total = sm[255];

    if (t == 0) {                    // publish immediately (b0: full prefix)
        unsigned long long post =
            ((b == 0 ? 2ull : 1ull) << 32) | (unsigned)total;
        __hip_atomic_store(&state[(size_t)b * 8], post,
                           __ATOMIC_RELAXED, __HIP_MEMORY_SCOPE_AGENT);
        if (b == 0) sbase = 0;
    }
    if (b > 0 && t < 64) {
        long long run = 0;
        int i = b - 1;
        while (true) {
            const int idx = i - t;
            unsigned long long s = (idx >= 0)
                ? __hip_atomic_load(&state[(size_t)idx * 8],
                                    __ATOMIC_RELAXED, __HIP_MEMORY_SCOPE_AGENT)
                : (2ull << 32);                      // virtual prefix-0 at -1
            const unsigned st = (unsigned)(s >> 32);
            const unsigned long long b0m = __ballot(st == 0u);
            const unsigned long long b2m = __ballot(st == 2u);
            if (b2m) {
                const int L = __ffsll((long long)b2m) - 1;   // nearest prefix
                const unsigned long long below =
                    (L == 63) ? ~0ull : ((1ull << (L + 1)) - 1ull);
                if (b0m & below) { __builtin_amdgcn_s_sleep(1); continue; }
                unsigned val = (t <= L) ? (unsigned)s : 0u;
#pragma unroll
                for (int o = 32; o; o >>= 1) val += __shfl_xor(val, o);
                run += val;
                break;
            } else if (b0m) {
                const int L0 = __ffsll((long long)b0m) - 1;  // consume < L0
                unsigned val = (t < L0) ? (unsigned)s : 0u;
#pragma unroll
                for (int o = 32; o; o >>= 1) val += __shfl_xor(val, o);
                run += val;
                i -= L0;
                if (L0 == 0) __builtin_amdgcn_s_sleep(1);
            } else {                                         // all aggregates
                unsigned val = (unsigned)s;
#pragma unroll
                for (int o = 32; o; o >>= 1) val += __shfl_xor(val, o);
                run += val;
                i -= 64;
            }
        }
        if (t == 0) {
            __hip_atomic_store(&state[(size_t)b * 8],
                               (2ull << 32) | (unsigned)(run + total),
                               __ATOMIC_RELAXED, __HIP_MEMORY_SCOPE_AGENT);
            sbase = (int)run;
        }
    }
    __syncthreads();
    const int base = sbase;

    if (g < NN) {
        const int s = base + (incl - v);
        start[g] = s;
        base4[g] = make_int4(s, s + cc[0], s + cc[0] + cc[1], s + cc[0] + cc[1] + cc[2]);
        float degs = (float)lowsum * (1.0f / 262144.0f);
        dinv[g] = rsqrtf(1.0f + degs);
    }
    if (g == 0) start[NN] = NE;
}

// -------- atomic-free CSR placement, 4 edges/thread vectorized:
// meta[base4[col][copy]+rank] = {bf16 dinv[row]*ew | u16 row}
__global__ __launch_bounds__(256) void meta_write(const int* __restrict__ row,
                                                  const int* __restrict__ col,
                                                  const float* __restrict__ ew,
                                                  const unsigned short* __restrict__ rank,
                                                  const int4* __restrict__ base4,
                                                  const float* __restrict__ dinv,
                                                  unsigned* __restrict__ meta) {
    const int e0 = (blockIdx.x * 256 + threadIdx.x) * 4;
    if (e0 >= NE) return;
    const int4 c4 = *(const int4*)(col + e0);
    const int4 r4 = *(const int4*)(row + e0);
    const float4 w4 = *(const float4*)(ew + e0);
    const ushort4 k4 = *(const ushort4*)(rank + e0);
    const int cs[4] = {c4.x, c4.y, c4.z, c4.w};
    const int rs[4] = {r4.x, r4.y, r4.z, r4.w};
    const float wsv[4] = {w4.x, w4.y, w4.z, w4.w};
    const unsigned short ks[4] = {k4.x, k4.y, k4.z, k4.w};
#pragma unroll
    for (int j = 0; j < 4; j++) {
        const int e = e0 + j;
        const int copy = (e >> 8) & 3;          // wave-uniform (256-edge runs)
        const int4 b4 = base4[cs[j]];
        const int base = (copy == 0) ? b4.x : (copy == 1) ? b4.y
                       : (copy == 2) ? b4.z : b4.w;
        const unsigned short wbf = f2bf(dinv[rs[j]] * wsv[j]);
        meta[base + ks[j]] = ((unsigned)wbf << 16) | (unsigned)rs[j];
    }
}

// ---------- pull aggregation: one wave per node, bf16 h, 8-way ILP, fused
// epilogue. meta is streamed nontemporally (no reuse) to keep L2 for hb.
__global__ __launch_bounds__(256) void aggregate(const int* __restrict__ start,
                                                 const unsigned* __restrict__ meta,
                                                 const unsigned short* __restrict__ hb,
                                                 const float* __restrict__ dinv,
                                                 const float* __restrict__ bias,
                                                 const float* __restrict__ alpha,
                                                 float* __restrict__ out) {
    int n = blockIdx.x * 4 + (threadIdx.x >> 6);
    if (n >= NN) return;
    n = __builtin_amdgcn_readfirstlane(n);
    const int lane = threadIdx.x & 63;
    const int s = __builtin_amdgcn_readfirstlane(start[n]);
    const int e = __builtin_amdgcn_readfirstlane(start[n + 1]);

    float A0[8], A1[8];
#pragma unroll
    for (int j = 0; j < 8; j++) { A0[j] = 0.f; A1[j] = 0.f; }

    int i = s;
    for (; i + 8 <= e; i += 8) {
        unsigned m[8], u[8];
#pragma unroll
        for (int j = 0; j < 8; j++) m[j] = __builtin_nontemporal_load(meta + i + j);
#pragma unroll
        for (int j = 0; j < 8; j++)
            u[j] = *(const unsigned*)(hb + (size_t)(m[j] & 0xFFFFu) * CD + lane * 2);
#pragma unroll
        for (int j = 0; j < 8; j++) {
            float w = __uint_as_float(m[j] & 0xFFFF0000u);
            A0[j] = fmaf(w, bf2f_lo(u[j]), A0[j]);
            A1[j] = fmaf(w, bf2f_hi(u[j]), A1[j]);
        }
    }
    for (; i < e; i++) {
        unsigned m = __builtin_nontemporal_load(meta + i);
        unsigned u = *(const unsigned*)(hb + (size_t)(m & 0xFFFFu) * CD + lane * 2);
        float w = __uint_as_float(m & 0xFFFF0000u);
        A0[0] = fmaf(w, bf2f_lo(u), A0[0]);
        A1[0] = fmaf(w, bf2f_hi(u), A1[0]);
    }
#pragma unroll
    for (int j = 1; j < 8; j++) { A0[0] += A0[j]; A1[0] += A1[j]; }

    const float dc = dinv[n];
    unsigned us = *(const unsigned*)(hb + (size_t)n * CD + lane * 2);
    const int ch = lane * 2;
    float o0 = dc * A0[0] + dc * dc * bf2f_lo(us) + bias[ch];
    float o1 = dc * A1[0] + dc * dc * bf2f_hi(us) + bias[ch + 1];
    o0 = o0 >= 0.f ? o0 : alpha[ch] * o0;
    o1 = o1 >= 0.f ? o1 : alpha[ch + 1] * o1;
    floatx2 o; o.x = o0; o.y = o1;
    __builtin_nontemporal_store(o, (floatx2*)(out + (size_t)n * CD + ch));
}

extern "C" void kernel_launch(void* const* d_in, const int* in_sizes, int n_in,
                              void* d_out, int out_size, void* d_ws, size_t ws_size,
                              hipStream_t stream) {
    const float* x     = (const float*)d_in[0];
    const int*   eidx  = (const int*)d_in[1];   // [2, NE]
    const float* ew    = (const float*)d_in[2];
    const float* Wm    = (const float*)d_in[3];
    const float* bias  = (const float*)d_in[4];
    const float* alpha = (const float*)d_in[5];
    const int* row = eidx;
    const int* col = eidx + NE;

    float* out = (float*)d_out;

    // workspace layout (bytes), no overlaps:
    char* ws = (char*)d_ws;
    unsigned* packedAll = (unsigned*)(ws);                   // 4*NN u32   [0, 800000)
    int*   start    = (int*)(ws + 800000);                   // NN+1 int   [800000, 1000004)
    float* dinv     = (float*)(ws + 1000064);                // NN f32     [1000064, 1200064)
    unsigned short* rank = (unsigned short*)(ws + 1200064);  // NE u16     [1200064, 2800064)
    int4*  base4    = (int4*)(ws + 2800064);                 // NN int4    [2800064, 3600064)
    unsigned* meta  = (unsigned*)(ws + 3600064);             // NE u32     [3600064, 6800064)
    unsigned short* Wt = (unsigned short*)(ws + 6800064);    // 128*256 bf16 [6800064, 6865600)
    unsigned long long* state = (unsigned long long*)(ws + 6865600); // NB*8 u64 [6865600, 6878144)
    unsigned short* hb = (unsigned short*)(ws + 6878208);    // 50176*128 bf16 [6878208, 19723264)

    prep          <<<NB + 32, 256, 0, stream>>>(Wm, Wt, packedAll, state);
    fused_gemm_hist<<<GEMM_BLOCKS + HIST_BLOCKS, 256, 0, stream>>>(
                        x, Wt, hb, col, ew, packedAll, rank);
    scan_lookback <<<NB, 256, 0, stream>>>(packedAll, state, start, base4, dinv);
    meta_write    <<<META_BLOCKS, 256, 0, stream>>>(row, col, ew, rank, base4, dinv, meta);
    aggregate     <<<(NN + 3) / 4, 256, 0, stream>>>(start, meta, hb, dinv, bias, alpha, out);
}